// Round 1
// baseline (240.918 us; speedup 1.0000x reference)
//
#include <hip/hip_runtime.h>
#include <hip/hip_bf16.h>
#include <math.h>

typedef __attribute__((ext_vector_type(8))) __bf16 bf16x8;
typedef __attribute__((ext_vector_type(4))) float f32x4;

// Problem constants
#define NN 4096
#define KN 48
#define HD 128
#define ED 384

// ws layout (bf16 element offsets for the bf16 region)
#define OFF_HVB    0         // h_V as bf16 [4096][128]
#define OFF_W1T    524288    // W1^T [128][512]  (W1T[h][e] = W1[e][h])
#define OFF_W2T    589824    // W2^T [128][128]  (W2T[g][h] = W2[h][g])
#define OFF_W3T    606208    // W3^T [128][128]  (W3T[h][g] = W3[g][h])
#define OFF_WINT   622592    // Win^T [512][128] (WinT[o][i] = Win[i][o])
#define OFF_WOUTT  688128    // Wout^T [128][512] (WoutT[h][g] = Wout[g][h])
#define NPREP      753664
#define OFF_DH_BYTES 1507328 // f32 dh [4096][128] after the bf16 region

__device__ __forceinline__ float gelu_f(float x) {
  return 0.5f * x * (1.0f + erff(x * 0.70710678118654752440f));
}

// ---------------- prep: bf16 casts + weight transposes ----------------
__global__ __launch_bounds__(256) void prep_kernel(
    const float* __restrict__ hV, const float* __restrict__ W1,
    const float* __restrict__ W2, const float* __restrict__ W3,
    const float* __restrict__ Wi, const float* __restrict__ Wo,
    __bf16* __restrict__ wsb)
{
  int i = blockIdx.x * 256 + threadIdx.x;
  float v;
  if (i < 524288)      { v = hV[i]; }
  else if (i < 589824) { int j=i-524288; int h=j>>9, e=j&511; v = W1[e*128+h]; }
  else if (i < 606208) { int j=i-589824; int g=j>>7, h=j&127; v = W2[h*128+g]; }
  else if (i < 622592) { int j=i-606208; int h=j>>7, g=j&127; v = W3[g*128+h]; }
  else if (i < 688128) { int j=i-622592; int o=j>>7, ii=j&127; v = Wi[ii*512+o]; }
  else                 { int j=i-688128; int h=j>>9, g=j&511; v = Wo[g*128+h]; }
  wsb[i] = (__bf16)v;
}

// ---------------- kernel 1: fused edge MLP + masked K-reduce ----------------
// block = 4 nodes = 192 edge tokens, 4 waves (wave w owns node n0+w's 48 rows)
__global__ __launch_bounds__(256, 2) void edge_mlp_kernel(
    const float* __restrict__ hE, const float* __restrict__ mask_att,
    const __bf16* __restrict__ wsb,
    const float* __restrict__ b1, const float* __restrict__ b2,
    const float* __restrict__ b3, float* __restrict__ dh)
{
  __shared__ char lds[65536];
  char* X  = lds;          // A region: 49152 B (192 rows, stride 128B or 256B)
  char* Wb = lds + 49152;  // W region: 16384 B (128 rows, stride 128B)

  const int tid = threadIdx.x;
  const int w = tid >> 6, lane = tid & 63;
  const int lo = lane & 15, hi = lane >> 4;
  const int n0 = blockIdx.x * 4;
  const int seg = tid & 7, rb = tid >> 3;   // staging coords

  const __bf16* hVb = wsb + OFF_HVB;
  const __bf16* W1T = wsb + OFF_W1T;
  const __bf16* W2T = wsb + OFF_W2T;
  const __bf16* W3T = wsb + OFF_W3T;

  f32x4 acc[3][8];
#pragma unroll
  for (int m=0;m<3;m++)
#pragma unroll
    for (int n=0;n<8;n++) { acc[m][n][0]=0.f; acc[m][n][1]=0.f; acc[m][n][2]=0.f; acc[m][n][3]=0.f; }

  // ---- GEMM1: h_EV[192,512] @ W1[512,128], BK=64, 8 chunks ----
  for (int kc = 0; kc < 8; ++kc) {
    if (kc) __syncthreads();
    // stage A chunk [192][64] bf16, stride 128B, XOR-swizzled
    if (kc < 2) {
      const int f0 = kc*64 + seg*8;     // feature within h_V part
#pragma unroll
      for (int p=0;p<6;p++) {
        int row = rb + 32*p;
        int nl = row / 48;
        bf16x8 v = *(const bf16x8*)(hVb + (n0+nl)*128 + f0);
        *(bf16x8*)(X + row*128 + ((seg*16) ^ ((row&7)<<4))) = v;
      }
    } else {
      const int e0 = kc*64 - 128 + seg*8;  // feature within h_E part
#pragma unroll
      for (int p=0;p<6;p++) {
        int row = rb + 32*p;
        int nl = row / 48;
        int kk = row - nl*48;
        const float* src = hE + (size_t)((n0+nl)*48 + kk)*384 + e0;
        float4 f1 = *(const float4*)src;
        float4 f2 = *(const float4*)(src+4);
        bf16x8 v;
        v[0]=(__bf16)f1.x; v[1]=(__bf16)f1.y; v[2]=(__bf16)f1.z; v[3]=(__bf16)f1.w;
        v[4]=(__bf16)f2.x; v[5]=(__bf16)f2.y; v[6]=(__bf16)f2.z; v[7]=(__bf16)f2.w;
        *(bf16x8*)(X + row*128 + ((seg*16) ^ ((row&7)<<4))) = v;
      }
    }
    // stage W1 chunk [128][64]
#pragma unroll
    for (int p=0;p<4;p++) {
      int h = rb + 32*p;
      bf16x8 v = *(const bf16x8*)(W1T + h*512 + kc*64 + seg*8);
      *(bf16x8*)(Wb + h*128 + ((seg*16) ^ ((h&7)<<4))) = v;
    }
    __syncthreads();
    // compute
#pragma unroll
    for (int ks=0; ks<2; ++ks) {
      const int kb = (ks*32 + hi*8)*2;
      bf16x8 a[3];
#pragma unroll
      for (int m=0;m<3;m++) {
        int row = w*48 + m*16 + lo;
        a[m] = *(const bf16x8*)(X + row*128 + (kb ^ ((row&7)<<4)));
      }
#pragma unroll
      for (int n=0;n<8;n++) {
        int hr = n*16 + lo;
        bf16x8 b = *(const bf16x8*)(Wb + hr*128 + (kb ^ ((hr&7)<<4)));
#pragma unroll
        for (int m=0;m<3;m++)
          acc[m][n] = __builtin_amdgcn_mfma_f32_16x16x32_bf16(a[m], b, acc[m][n], 0,0,0);
      }
    }
  }
  __syncthreads();

  // ---- layers 2 and 3: A[192,128] @ W[128,128], BK=64 ----
  const __bf16* WTs[2] = {W2T, W3T};
  const float*  bps[2] = {b1, b2};
#pragma unroll
  for (int layer=0; layer<2; ++layer) {
    // gelu(acc + b) -> X as A [192][128] bf16 (stride 256B), reset acc.
    // Each wave touches only its own 48 rows -> no cross-wave hazard on X.
#pragma unroll
    for (int n=0;n<8;n++) {
      float bc = bps[layer][n*16 + lo];
      int colb = (n*16 + lo)*2;
#pragma unroll
      for (int m=0;m<3;m++)
#pragma unroll
        for (int i=0;i<4;i++) {
          int row = w*48 + m*16 + hi*4 + i;
          float g = gelu_f(acc[m][n][i] + bc);
          *(__bf16*)(X + row*256 + (colb ^ ((row&7)<<4))) = (__bf16)g;
          acc[m][n][i] = 0.f;
        }
    }
    const __bf16* WT = WTs[layer];
    for (int kc=0; kc<2; ++kc) {
      // stage W chunk [128][64] (previous compute's readers are behind a barrier)
#pragma unroll
      for (int p=0;p<4;p++) {
        int h = rb + 32*p;
        bf16x8 v = *(const bf16x8*)(WT + h*128 + kc*64 + seg*8);
        *(bf16x8*)(Wb + h*128 + ((seg*16) ^ ((h&7)<<4))) = v;
      }
      __syncthreads();
#pragma unroll
      for (int ks=0; ks<2; ++ks) {
        const int kbA = (kc*64 + ks*32 + hi*8)*2;
        const int kbW = (ks*32 + hi*8)*2;
        bf16x8 a[3];
#pragma unroll
        for (int m=0;m<3;m++) {
          int row = w*48 + m*16 + lo;
          a[m] = *(const bf16x8*)(X + row*256 + (kbA ^ ((row&7)<<4)));
        }
#pragma unroll
        for (int n=0;n<8;n++) {
          int hr = n*16 + lo;
          bf16x8 b = *(const bf16x8*)(Wb + hr*128 + (kbW ^ ((hr&7)<<4)));
#pragma unroll
          for (int m=0;m<3;m++)
            acc[m][n] = __builtin_amdgcn_mfma_f32_16x16x32_bf16(a[m], b, acc[m][n], 0,0,0);
        }
      }
      __syncthreads();
    }
  }

  // ---- epilogue: + b3, * mask_attend, sum over the node's 48 rows, /SCALE ----
  const int node = n0 + w;
  float msk[12];
#pragma unroll
  for (int m=0;m<3;m++)
#pragma unroll
    for (int i=0;i<4;i++)
      msk[m*4+i] = mask_att[node*48 + m*16 + hi*4 + i];

#pragma unroll
  for (int n=0;n<8;n++) {
    float bc = b3[n*16 + lo];
    float s = 0.f;
#pragma unroll
    for (int m=0;m<3;m++)
#pragma unroll
      for (int i=0;i<4;i++)
        s += (acc[m][n][i] + bc) * msk[m*4+i];
    s += __shfl_xor(s, 16);
    s += __shfl_xor(s, 32);
    if (hi == 0)
      dh[node*128 + n*16 + lo] = s * (1.0f/30.0f);
  }
}

// ---------------- kernel 2: LN1 + FFN + LN2 + mask ----------------
// block = 16 nodes, 4 waves
__global__ __launch_bounds__(256, 2) void node_ffn_kernel(
    const float* __restrict__ hV, const float* __restrict__ maskV,
    const __bf16* __restrict__ wsb, const float* __restrict__ dh,
    const float* __restrict__ Winb, const float* __restrict__ Woutb,
    const float* __restrict__ ns1, const float* __restrict__ no1,
    const float* __restrict__ ns2, const float* __restrict__ no2,
    float* __restrict__ out)
{
  __shared__ char lds[36864];
  char*  xA  = lds;                    // [16][256B] bf16, swizzled
  float* hvn = (float*)(lds + 4096);   // [16][128] f32 (h_Vn after LN1)
  char*  A2  = lds + 12288;            // [16][1024B] bf16, swizzled
  float* red = (float*)(lds + 28672);  // [16][128] f32 (FFN output)

  const __bf16* WinT  = wsb + OFF_WINT;
  const __bf16* WoutT = wsb + OFF_WOUTT;

  const int tid = threadIdx.x;
  const int w = tid >> 6, lane = tid & 63;
  const int lo = lane & 15, hi = lane >> 4;
  const int n0 = blockIdx.x * 16;

  const int row = tid >> 4;   // 0..15 (node within block)
  const int sg  = tid & 15;   // 0..15 (8-feature segment)
  const int node = n0 + row;

  // Phase 0: x = h_V + dh, LN1 -> hvn (f32) and xA (bf16)
  {
    const float* pv = hV + node*128 + sg*8;
    const float* pd = dh + node*128 + sg*8;
    float4 a0 = *(const float4*)pv;
    float4 a1 = *(const float4*)(pv+4);
    float4 d0 = *(const float4*)pd;
    float4 d1 = *(const float4*)(pd+4);
    float x[8] = {a0.x+d0.x, a0.y+d0.y, a0.z+d0.z, a0.w+d0.w,
                  a1.x+d1.x, a1.y+d1.y, a1.z+d1.z, a1.w+d1.w};
    float s=0.f, sq=0.f;
#pragma unroll
    for (int j=0;j<8;j++){ s += x[j]; sq += x[j]*x[j]; }
#pragma unroll
    for (int off=8; off>=1; off>>=1){ s += __shfl_xor(s,off); sq += __shfl_xor(sq,off); }
    float mean = s*(1.f/128.f);
    float var  = sq*(1.f/128.f) - mean*mean;
    float rs = rsqrtf(var + 1e-5f);
    bf16x8 vb;
    float yv[8];
#pragma unroll
    for (int j=0;j<8;j++){
      int col = sg*8 + j;
      float y = (x[j]-mean)*rs*ns1[col] + no1[col];
      yv[j] = y; vb[j] = (__bf16)y;
    }
    *(float4*)(hvn + row*128 + sg*8)     = make_float4(yv[0],yv[1],yv[2],yv[3]);
    *(float4*)(hvn + row*128 + sg*8 + 4) = make_float4(yv[4],yv[5],yv[6],yv[7]);
    *(bf16x8*)(xA + row*256 + ((sg*16) ^ ((row&7)<<4))) = vb;
  }
  __syncthreads();

  // Phase 1: [16,128] @ Win -> [16,512]; wave w owns output cols w*128..+127
  f32x4 acc[8];
#pragma unroll
  for (int n=0;n<8;n++) { acc[n][0]=0.f; acc[n][1]=0.f; acc[n][2]=0.f; acc[n][3]=0.f; }
#pragma unroll
  for (int ks=0;ks<4;ks++){
    const int kb = (ks*32 + hi*8)*2;
    bf16x8 a = *(const bf16x8*)(xA + lo*256 + (kb ^ ((lo&7)<<4)));
#pragma unroll
    for (int n=0;n<8;n++){
      int colg = w*128 + n*16 + lo;
      bf16x8 b = *(const bf16x8*)(WinT + colg*128 + ks*32 + hi*8);
      acc[n] = __builtin_amdgcn_mfma_f32_16x16x32_bf16(a, b, acc[n], 0,0,0);
    }
  }
  // Phase 2: gelu -> A2 [16][512] bf16 (stride 1024B, swizzled)
#pragma unroll
  for (int n=0;n<8;n++){
    int col = w*128 + n*16 + lo;
    float bc = Winb[col];
#pragma unroll
    for (int i=0;i<4;i++){
      int r2 = hi*4 + i;
      float g = gelu_f(acc[n][i] + bc);
      *(__bf16*)(A2 + r2*1024 + ((col*2) ^ ((r2&7)<<4))) = (__bf16)g;
    }
  }
  __syncthreads();

  // Phase 3: [16,512] @ Wout -> [16,128]; wave w owns output cols w*32..+31
  f32x4 acc2[2];
  acc2[0][0]=0.f; acc2[0][1]=0.f; acc2[0][2]=0.f; acc2[0][3]=0.f;
  acc2[1][0]=0.f; acc2[1][1]=0.f; acc2[1][2]=0.f; acc2[1][3]=0.f;
#pragma unroll
  for (int ks=0;ks<16;ks++){
    const int kb = (ks*32 + hi*8)*2;
    bf16x8 a = *(const bf16x8*)(A2 + lo*1024 + (kb ^ ((lo&7)<<4)));
#pragma unroll
    for (int n=0;n<2;n++){
      int gc = w*32 + n*16 + lo;
      bf16x8 b = *(const bf16x8*)(WoutT + gc*512 + ks*32 + hi*8);
      acc2[n] = __builtin_amdgcn_mfma_f32_16x16x32_bf16(a, b, acc2[n], 0,0,0);
    }
  }
  // Phase 4: + bias -> red
#pragma unroll
  for (int n=0;n<2;n++){
    int col = w*32 + n*16 + lo;
    float bc = Woutb[col];
#pragma unroll
    for (int i=0;i<4;i++){
      int r2 = hi*4 + i;
      red[r2*128 + col] = acc2[n][i] + bc;
    }
  }
  __syncthreads();

  // Phase 5: LN2(hvn + red) * mask_V -> out
  {
    const float* ph = hvn + row*128 + sg*8;
    const float* pr = red + row*128 + sg*8;
    float4 h0 = *(const float4*)ph;
    float4 h1 = *(const float4*)(ph+4);
    float4 r0 = *(const float4*)pr;
    float4 r1 = *(const float4*)(pr+4);
    float x[8] = {h0.x+r0.x, h0.y+r0.y, h0.z+r0.z, h0.w+r0.w,
                  h1.x+r1.x, h1.y+r1.y, h1.z+r1.z, h1.w+r1.w};
    float s=0.f, sq=0.f;
#pragma unroll
    for (int j=0;j<8;j++){ s += x[j]; sq += x[j]*x[j]; }
#pragma unroll
    for (int off=8; off>=1; off>>=1){ s += __shfl_xor(s,off); sq += __shfl_xor(sq,off); }
    float mean = s*(1.f/128.f);
    float var  = sq*(1.f/128.f) - mean*mean;
    float rs = rsqrtf(var + 1e-5f);
    float mv = maskV[node];
    float o[8];
#pragma unroll
    for (int j=0;j<8;j++){
      int col = sg*8 + j;
      o[j] = mv * ((x[j]-mean)*rs*ns2[col] + no2[col]);
    }
    *(float4*)(out + node*128 + sg*8)     = make_float4(o[0],o[1],o[2],o[3]);
    *(float4*)(out + node*128 + sg*8 + 4) = make_float4(o[4],o[5],o[6],o[7]);
  }
}

extern "C" void kernel_launch(void* const* d_in, const int* in_sizes, int n_in,
                              void* d_out, int out_size, void* d_ws, size_t ws_size,
                              hipStream_t stream)
{
  (void)in_sizes; (void)n_in; (void)out_size; (void)ws_size;
  const float* hV   = (const float*)d_in[0];
  const float* hE   = (const float*)d_in[1];
  const float* mV   = (const float*)d_in[2];
  const float* mAtt = (const float*)d_in[3];
  const float* W1   = (const float*)d_in[4];
  const float* b1   = (const float*)d_in[5];
  const float* W2   = (const float*)d_in[6];
  const float* b2   = (const float*)d_in[7];
  const float* W3   = (const float*)d_in[8];
  const float* b3   = (const float*)d_in[9];
  const float* Win  = (const float*)d_in[10];
  const float* binb = (const float*)d_in[11];
  const float* Wout = (const float*)d_in[12];
  const float* bout = (const float*)d_in[13];
  const float* ns1  = (const float*)d_in[14];
  const float* no1  = (const float*)d_in[15];
  const float* ns2  = (const float*)d_in[16];
  const float* no2  = (const float*)d_in[17];

  __bf16* wsb = (__bf16*)d_ws;
  float* dh   = (float*)((char*)d_ws + OFF_DH_BYTES);
  float* out  = (float*)d_out;

  prep_kernel<<<NPREP/256, 256, 0, stream>>>(hV, W1, W2, W3, Win, Wout, wsb);
  edge_mlp_kernel<<<1024, 256, 0, stream>>>(hE, mAtt, wsb, b1, b2, b3, dh);
  node_ffn_kernel<<<256, 256, 0, stream>>>(hV, mV, wsb, dh, binb, bout,
                                           ns1, no1, ns2, no2, out);
}